// Round 4
// baseline (8051.829 us; speedup 1.0000x reference)
//
#include <hip/hip_runtime.h>
#include <math.h>

// CRsAE1D: 30 FISTA iterations. y [32,1,8192] f32, H [64,1,31] f32.
// out = concat(y_hat [32,8192], x [32,64,8162]) f32.
//
// One fused kernel per iteration. Each block owns (batch b, 256-wide m-tile).
// Wave-independent schedule: wave w owns channels [16w,16w+16), processed in
// 4-channel chunks: phase1 (x update -> xs rows) then phase2 (Hop gather of
// those rows into per-lane registers). Producer/consumer deps are intra-wave
// -> ONE __syncthreads total (after staging). Hop partials accumulate in
// registers across chunks, flushed with one global atomicAdd per output.
// State = x_new only (ping-pong ws / d_out-x); x_tmp recomputed from the two
// streams. t=29 uses c1=0 and rnext=yhat so Hop(x_final) lands in y_hat.

#define BB   32
#define CCH  64
#define KF   31
#define NN   8192
#define MM   8162
#define TT   30
#define TILE 256
#define NT   32
#define HS_P 33          // Hs pitch: (33c+k)%32=(c+k)%32 -> bank spread
#define XS_C 330         // covers F(319)=328

#define BCM ((size_t)BB * CCH * MM)
#define BN  ((size_t)BB * NN)

// LDS swizzle: +1 slot every 32 breaks power-of-2 stride conflicts
__device__ __forceinline__ int F(int i) { return i + (i >> 5); }

__global__ __launch_bounds__(256, 4) void step_kernel(
    const float* __restrict__ y, const float* __restrict__ Hg,
    const float* __restrict__ xA,  // x_new_{t-1}
    float* __restrict__ xW,        // read: x_new_{t-2}; write: x_new_t
    const float* __restrict__ rcur, float* __restrict__ rnext,
    float* __restrict__ rzero, float c0, float c1)
{
    __shared__ float Hs[CCH * HS_P];   //  8448 B
    __shared__ float resv[296];        //  1184 B (swizzled, logical 288)
    __shared__ float xs[16 * XS_C];    // 21120 B: [wave][4 ch rows][330]

    const int tid = threadIdx.x;
    const int m0  = blockIdx.x * TILE;
    const int b   = blockIdx.y;
    const size_t yb = (size_t)b * NN;

    // ---- staging (all threads), then the ONLY barrier ----
    for (int s = tid; s < CCH * HS_P; s += 256) {
        int c = s / HS_P, k = s - c * HS_P;
        Hs[s] = (k < KF) ? Hg[c * KF + k] : 0.f;
    }
    for (int i = tid; i < 288; i += 256) {
        int n = m0 + i; float v = 0.f;
        if (i < 286 && n < NN) v = y[yb + n] - rcur[yb + n];
        resv[F(i)] = v;
    }
    for (int s = tid; s < 16 * 64; s += 256) {   // zero xs halos [0,32)+[288,320)
        int row = s >> 6, q = s & 63;
        int raw = (q < 32) ? q : (q + 256);
        xs[row * XS_C + F(raw)] = 0.f;
    }
    rzero[yb + m0 + tid] = 0.f;   // pre-zero the t+2 accumulator
    __syncthreads();

    const int wv    = tid >> 6, lane = tid & 63;
    const int cb2   = lane >> 4, lanem = lane & 15;   // phase 1 mapping
    const int ogi   = lane & 31, csi   = lane >> 5;   // phase 2 mapping
    const int ib    = ogi * 9;

    float r9[9];
    #pragma unroll
    for (int j = 0; j < 9; ++j) r9[j] = 0.f;

    #pragma unroll 1
    for (int r = 0; r < 4; ++r) {
        // ---- phase 1: x update for channels 16w+4r+{0..3} ----
        {
            const int c = wv * 16 + r * 4 + cb2;
            float* xrow = xs + (wv * 4 + cb2) * XS_C;
            const size_t xg = ((size_t)(b * CCH + c)) * MM;
            const float* hr = Hs + c * HS_P;
            #pragma unroll
            for (int p = 0; p < 2; ++p) {
                const int lb = p * 128 + lanem * 8;
                const int mb = m0 + lb;
                const size_t g = xg + mb;
                float w[8], acc[8];
                #pragma unroll
                for (int j = 0; j < 8; ++j) { w[j] = resv[F(lb + j)]; acc[j] = 0.f; }
                if (mb + 7 < MM) {
                    float av[8], bv[8];
                    #pragma unroll
                    for (int j = 0; j < 8; j += 2) {
                        float2 t2 = *(const float2*)(xA + g + j);
                        av[j] = t2.x; av[j + 1] = t2.y;
                    }
                    #pragma unroll
                    for (int j = 0; j < 8; j += 2) {
                        float2 t2 = *(const float2*)(xW + g + j);
                        bv[j] = t2.x; bv[j + 1] = t2.y;
                    }
                    #pragma unroll
                    for (int k = 0; k < KF; ++k) {
                        float h = hr[k];
                        #pragma unroll
                        for (int j = 0; j < 8; ++j) acc[j] = fmaf(w[(k + j) & 7], h, acc[j]);
                        w[k & 7] = resv[F(lb + k + 8)];
                    }
                    float xn[8];
                    #pragma unroll
                    for (int j = 0; j < 8; ++j) {
                        float xt = fmaf(c0, av[j] - bv[j], av[j]);      // x_tmp_t
                        xn[j] = fmaxf(fmaf(acc[j], 0.2f, xt) - 0.02f, 0.f);
                        float x1 = fmaf(c1, xn[j] - av[j], xn[j]);      // x_tmp_{t+1}
                        xrow[F(32 + lb + j)] = x1;
                    }
                    #pragma unroll
                    for (int j = 0; j < 8; j += 2)
                        *(float2*)(xW + g + j) = make_float2(xn[j], xn[j + 1]);
                } else {
                    #pragma unroll
                    for (int k = 0; k < KF; ++k) {
                        float h = hr[k];
                        #pragma unroll
                        for (int j = 0; j < 8; ++j) acc[j] = fmaf(w[(k + j) & 7], h, acc[j]);
                        w[k & 7] = resv[F(lb + k + 8)];
                    }
                    #pragma unroll
                    for (int j = 0; j < 8; ++j) {
                        float x1 = 0.f;
                        if (mb + j < MM) {
                            float a = xA[g + j], b2 = xW[g + j];
                            float xt = fmaf(c0, a - b2, a);
                            float v  = fmaxf(fmaf(acc[j], 0.2f, xt) - 0.02f, 0.f);
                            xW[g + j] = v;
                            x1 = fmaf(c1, v - a, v);
                        }
                        xrow[F(32 + lb + j)] = x1;
                    }
                }
            }
        }

        // ---- phase 2: Hop gather of the same 4 channels (intra-wave dep) ----
        #pragma unroll
        for (int cc = 0; cc < 2; ++cc) {
            const int cl = 2 * csi + cc;                    // channel-in-chunk
            const float* xr = xs + (wv * 4 + cl) * XS_C;
            const float* hr = Hs + (wv * 16 + r * 4 + cl) * HS_P;
            float w[16];
            #pragma unroll
            for (int j = 0; j < 9; ++j) w[j] = xr[F(32 + ib + j)];
            #pragma unroll
            for (int k = 0; k < KF; ++k) {
                float h = hr[k];
                #pragma unroll
                for (int j = 0; j < 9; ++j)
                    r9[j] = fmaf(w[(j - k) & 15], h, r9[j]);
                w[(15 - k) & 15] = xr[F(31 + ib - k)];      // x[ib-k-1], in-bounds
            }
        }
    }

    // ---- flush register partials: one global atomic per output ----
    #pragma unroll
    for (int j = 0; j < 9; ++j) {
        int i = ib + j, n = m0 + i;
        if (i < 286 && n < NN) atomicAdd(&rnext[yb + n], r9[j]);
    }
}

extern "C" void kernel_launch(void* const* d_in, const int* in_sizes, int n_in,
                              void* d_out, int out_size, void* d_ws, size_t ws_size,
                              hipStream_t stream) {
    const float* y  = (const float*)d_in[0];
    const float* Hg = (const float*)d_in[1];

    float* out  = (float*)d_out;
    float* yhat = out;               // B*N
    float* xout = out + BN;          // B*C*M : ping-pong buffer X1 (odd t)
    float* x0w  = (float*)d_ws;      // B*C*M : ping-pong buffer X0 (even t)
    float* r0   = x0w + BCM;         // 3 rotating Hop accumulators, B*N each
    float* r1   = r0 + BN;
    float* r2   = r1 + BN;
    float* rb[3] = {r0, r1, r2};

    hipMemsetAsync(x0w, 0, (BCM + 3 * BN) * sizeof(float), stream);
    hipMemsetAsync(out, 0, (BN + BCM) * sizeof(float), stream);

    dim3 grid(NT, BB);   // 32 tiles x 32 batch = 1024 blocks (4/CU exact)
    float s = 1.f, beta_prev = 0.f;
    for (int t = 0; t < TT; ++t) {
        float snew = (1.f + sqrtf(1.f + 4.f * s * s)) * 0.5f;
        float beta = (s - 1.f) / snew;
        float c1v = (t == TT - 1) ? 0.f : beta;          // t=29: Hop(x_new)=y_hat
        float* xWt       = (t & 1) ? xout : x0w;
        const float* xAt = (t & 1) ? x0w  : xout;
        float* rnext = (t == TT - 1) ? yhat : rb[(t + 1) % 3];
        step_kernel<<<grid, 256, 0, stream>>>(y, Hg, xAt, xWt,
            rb[t % 3], rnext, rb[(t + 2) % 3], beta_prev, c1v);
        beta_prev = beta;
        s = snew;
    }
}

// Round 5
// 4257.992 us; speedup vs baseline: 1.8910x; 1.8910x over previous
//
#include <hip/hip_runtime.h>
#include <math.h>

// CRsAE1D: 30 FISTA iterations. y [32,1,8192] f32, H [64,1,31] f32.
// out = concat(y_hat [32,8192], x [32,64,8162]) f32.
//
// One fused kernel per iteration. Each block owns (batch b, 256-wide m-tile).
// Wave-independent schedule: wave w owns channels [16w,16w+16), processed in
// 4-channel chunks: phase1 (x update -> xs rows) then phase2 (Hop gather of
// those rows into per-lane registers). Producer/consumer deps are intra-wave
// -> ONE __syncthreads total (after staging). Hop partials accumulate in
// registers across chunks, flushed with one global atomicAdd per output.
// State = x_new only (ping-pong ws / d_out-x); x_tmp recomputed from the two
// streams. t=29 uses c1=0 and rnext=yhat so Hop(x_final) lands in y_hat.
//
// NOTE: no min-waves clause in __launch_bounds__ — round 4 showed (256,4)
// forces VGPR=64 on this compiler (not the documented 128) and the resulting
// spill quadrupled HBM traffic (147->604 MB/iter). Unconstrained allocation
// (round 2: VGPR=164, zero spill) is strictly better here.

#define BB   32
#define CCH  64
#define KF   31
#define NN   8192
#define MM   8162
#define TT   30
#define TILE 256
#define NT   32
#define HS_P 33          // Hs pitch: (33c+k)%32=(c+k)%32 -> bank spread
#define XS_C 330         // covers F(319)=328

#define BCM ((size_t)BB * CCH * MM)
#define BN  ((size_t)BB * NN)

// LDS swizzle: +1 slot every 32 breaks power-of-2 stride conflicts
__device__ __forceinline__ int F(int i) { return i + (i >> 5); }

__global__ __launch_bounds__(256) void step_kernel(
    const float* __restrict__ y, const float* __restrict__ Hg,
    const float* __restrict__ xA,  // x_new_{t-1}
    float* __restrict__ xW,        // read: x_new_{t-2}; write: x_new_t
    const float* __restrict__ rcur, float* __restrict__ rnext,
    float* __restrict__ rzero, float c0, float c1)
{
    __shared__ float Hs[CCH * HS_P];   //  8448 B
    __shared__ float resv[296];        //  1184 B (swizzled, logical 288)
    __shared__ float xs[16 * XS_C];    // 21120 B: [wave][4 ch rows][330]

    const int tid = threadIdx.x;
    const int m0  = blockIdx.x * TILE;
    const int b   = blockIdx.y;
    const size_t yb = (size_t)b * NN;

    // ---- staging (all threads), then the ONLY barrier ----
    for (int s = tid; s < CCH * HS_P; s += 256) {
        int c = s / HS_P, k = s - c * HS_P;
        Hs[s] = (k < KF) ? Hg[c * KF + k] : 0.f;
    }
    for (int i = tid; i < 288; i += 256) {
        int n = m0 + i; float v = 0.f;
        if (i < 286 && n < NN) v = y[yb + n] - rcur[yb + n];
        resv[F(i)] = v;
    }
    for (int s = tid; s < 16 * 64; s += 256) {   // zero xs halos [0,32)+[288,320)
        int row = s >> 6, q = s & 63;
        int raw = (q < 32) ? q : (q + 256);
        xs[row * XS_C + F(raw)] = 0.f;
    }
    rzero[yb + m0 + tid] = 0.f;   // pre-zero the t+2 accumulator
    __syncthreads();

    const int wv    = tid >> 6, lane = tid & 63;
    const int cb2   = lane >> 4, lanem = lane & 15;   // phase 1 mapping
    const int ogi   = lane & 31, csi   = lane >> 5;   // phase 2 mapping
    const int ib    = ogi * 9;

    float r9[9];
    #pragma unroll
    for (int j = 0; j < 9; ++j) r9[j] = 0.f;

    #pragma unroll 1
    for (int r = 0; r < 4; ++r) {
        // ---- phase 1: x update for channels 16w+4r+{0..3} ----
        {
            const int c = wv * 16 + r * 4 + cb2;
            float* xrow = xs + (wv * 4 + cb2) * XS_C;
            const size_t xg = ((size_t)(b * CCH + c)) * MM;
            const float* hr = Hs + c * HS_P;
            #pragma unroll
            for (int p = 0; p < 2; ++p) {
                const int lb = p * 128 + lanem * 8;
                const int mb = m0 + lb;
                const size_t g = xg + mb;
                float w[8], acc[8];
                #pragma unroll
                for (int j = 0; j < 8; ++j) { w[j] = resv[F(lb + j)]; acc[j] = 0.f; }
                if (mb + 7 < MM) {
                    float av[8], bv[8];
                    #pragma unroll
                    for (int j = 0; j < 8; j += 2) {
                        float2 t2 = *(const float2*)(xA + g + j);
                        av[j] = t2.x; av[j + 1] = t2.y;
                    }
                    #pragma unroll
                    for (int j = 0; j < 8; j += 2) {
                        float2 t2 = *(const float2*)(xW + g + j);
                        bv[j] = t2.x; bv[j + 1] = t2.y;
                    }
                    #pragma unroll
                    for (int k = 0; k < KF; ++k) {
                        float h = hr[k];
                        #pragma unroll
                        for (int j = 0; j < 8; ++j) acc[j] = fmaf(w[(k + j) & 7], h, acc[j]);
                        w[k & 7] = resv[F(lb + k + 8)];
                    }
                    float xn[8];
                    #pragma unroll
                    for (int j = 0; j < 8; ++j) {
                        float xt = fmaf(c0, av[j] - bv[j], av[j]);      // x_tmp_t
                        xn[j] = fmaxf(fmaf(acc[j], 0.2f, xt) - 0.02f, 0.f);
                        float x1 = fmaf(c1, xn[j] - av[j], xn[j]);      // x_tmp_{t+1}
                        xrow[F(32 + lb + j)] = x1;
                    }
                    #pragma unroll
                    for (int j = 0; j < 8; j += 2)
                        *(float2*)(xW + g + j) = make_float2(xn[j], xn[j + 1]);
                } else {
                    #pragma unroll
                    for (int k = 0; k < KF; ++k) {
                        float h = hr[k];
                        #pragma unroll
                        for (int j = 0; j < 8; ++j) acc[j] = fmaf(w[(k + j) & 7], h, acc[j]);
                        w[k & 7] = resv[F(lb + k + 8)];
                    }
                    #pragma unroll
                    for (int j = 0; j < 8; ++j) {
                        float x1 = 0.f;
                        if (mb + j < MM) {
                            float a = xA[g + j], b2 = xW[g + j];
                            float xt = fmaf(c0, a - b2, a);
                            float v  = fmaxf(fmaf(acc[j], 0.2f, xt) - 0.02f, 0.f);
                            xW[g + j] = v;
                            x1 = fmaf(c1, v - a, v);
                        }
                        xrow[F(32 + lb + j)] = x1;
                    }
                }
            }
        }

        // ---- phase 2: Hop gather of the same 4 channels (intra-wave dep) ----
        #pragma unroll
        for (int cc = 0; cc < 2; ++cc) {
            const int cl = 2 * csi + cc;                    // channel-in-chunk
            const float* xr = xs + (wv * 4 + cl) * XS_C;
            const float* hr = Hs + (wv * 16 + r * 4 + cl) * HS_P;
            float w[16];
            #pragma unroll
            for (int j = 0; j < 9; ++j) w[j] = xr[F(32 + ib + j)];
            #pragma unroll
            for (int k = 0; k < KF; ++k) {
                float h = hr[k];
                #pragma unroll
                for (int j = 0; j < 9; ++j)
                    r9[j] = fmaf(w[(j - k) & 15], h, r9[j]);
                w[(15 - k) & 15] = xr[F(31 + ib - k)];      // x[ib-k-1], in-bounds
            }
        }
    }

    // ---- flush register partials: one global atomic per output ----
    #pragma unroll
    for (int j = 0; j < 9; ++j) {
        int i = ib + j, n = m0 + i;
        if (i < 286 && n < NN) atomicAdd(&rnext[yb + n], r9[j]);
    }
}

extern "C" void kernel_launch(void* const* d_in, const int* in_sizes, int n_in,
                              void* d_out, int out_size, void* d_ws, size_t ws_size,
                              hipStream_t stream) {
    const float* y  = (const float*)d_in[0];
    const float* Hg = (const float*)d_in[1];

    float* out  = (float*)d_out;
    float* yhat = out;               // B*N
    float* xout = out + BN;          // B*C*M : ping-pong buffer X1 (odd t)
    float* x0w  = (float*)d_ws;      // B*C*M : ping-pong buffer X0 (even t)
    float* r0   = x0w + BCM;         // 3 rotating Hop accumulators, B*N each
    float* r1   = r0 + BN;
    float* r2   = r1 + BN;
    float* rb[3] = {r0, r1, r2};

    hipMemsetAsync(x0w, 0, (BCM + 3 * BN) * sizeof(float), stream);
    hipMemsetAsync(out, 0, (BN + BCM) * sizeof(float), stream);

    dim3 grid(NT, BB);   // 32 tiles x 32 batch = 1024 blocks
    float s = 1.f, beta_prev = 0.f;
    for (int t = 0; t < TT; ++t) {
        float snew = (1.f + sqrtf(1.f + 4.f * s * s)) * 0.5f;
        float beta = (s - 1.f) / snew;
        float c1v = (t == TT - 1) ? 0.f : beta;          // t=29: Hop(x_new)=y_hat
        float* xWt       = (t & 1) ? xout : x0w;
        const float* xAt = (t & 1) ? x0w  : xout;
        float* rnext = (t == TT - 1) ? yhat : rb[(t + 1) % 3];
        step_kernel<<<grid, 256, 0, stream>>>(y, Hg, xAt, xWt,
            rb[t % 3], rnext, rb[(t + 2) % 3], beta_prev, c1v);
        beta_prev = beta;
        s = snew;
    }
}

// Round 6
// 2246.977 us; speedup vs baseline: 3.5834x; 1.8950x over previous
//
#include <hip/hip_runtime.h>
#include <math.h>

// CRsAE1D: 30 FISTA iterations. y [32,1,8192] f32, H [64,1,31] f32.
// out = concat(y_hat [32,8192], x [32,64,8162]) f32.
//
// One fused kernel per iteration; block = (batch b, 256-wide m-tile); wave w
// owns channels [16w,16w+16) in 4-channel chunks: phase1 (x update -> xs)
// then phase2 (Hop gather -> per-lane r9). Intra-wave deps only; 2 barriers
// total (post-staging, pre-flush).
//
// Round-6 restructure: all LDS rings use prefetch DISTANCE-8 (16-slot ring,
// loads issued 2 four-tap blocks before use) and h-taps are double-buffered
// one block ahead — round 5 showed distance-1 load->use chains exposed
// ~100cy LDS latency per tap (VALUBusy 18%, dur 172us >> 50K-cycle issue
// work). Swizzle is i+4*(i>>5) so quad loads stay 16B-aligned -> b128.
// Hop flush via per-wave LDS rows + 286 global atomics/block (round 5's
// 9-per-thread global atomics cost +72MB HBM writes).

#define BB   32
#define CCH  64
#define KF   31
#define NN   8192
#define MM   8162
#define TT   30
#define TILE 256
#define NT   32
#define HS_P 37          // Hs pitch: banks differ by 5 per channel
#define XS_C 356         // covers Fi(319)=355
#define RACC_P 292

#define BCM ((size_t)BB * CCH * MM)
#define BN  ((size_t)BB * NN)

// swizzle: +4 slots every 32 -> quad-aligned, breaks power-of-2 strides
__device__ __forceinline__ int Fi(int i) { return i + ((i >> 5) << 2); }

__global__ __launch_bounds__(256) void step_kernel(
    const float* __restrict__ y, const float* __restrict__ Hg,
    const float* __restrict__ xA,  // x_new_{t-1}
    float* __restrict__ xW,        // read: x_new_{t-2}; write: x_new_t
    const float* __restrict__ rcur, float* __restrict__ rnext,
    float* __restrict__ rzero, float c0, float c1)
{
    __shared__ __attribute__((aligned(16))) float Hs[CCH * HS_P];  //  9472 B
    __shared__ __attribute__((aligned(16))) float resv[320];       //  1280 B
    __shared__ __attribute__((aligned(16))) float xs[16 * XS_C];   // 22784 B
    __shared__ __attribute__((aligned(16))) float racc[4 * RACC_P];//  4672 B

    const int tid = threadIdx.x;
    const int m0  = blockIdx.x * TILE;
    const int b   = blockIdx.y;
    const size_t yb = (size_t)b * NN;

    // ---- staging ----
    for (int s = tid; s < CCH * HS_P; s += 256) {
        int c = s / HS_P, k = s - c * HS_P;
        Hs[s] = (k < KF) ? Hg[c * KF + k] : 0.f;
    }
    for (int i = tid; i < 288; i += 256) {
        int n = m0 + i; float v = 0.f;
        if (i < 286 && n < NN) v = y[yb + n] - rcur[yb + n];
        resv[Fi(i)] = v;
    }
    for (int s = tid; s < 16 * 64; s += 256) {   // xs halos raw [0,32)+[288,320)
        int row = s >> 6, q = s & 63;
        int raw = (q < 32) ? q : (q + 256);
        xs[row * XS_C + Fi(raw)] = 0.f;
    }
    rzero[yb + m0 + tid] = 0.f;
    __syncthreads();

    const int wv    = tid >> 6, lane = tid & 63;
    const int cb2   = lane >> 4, lanem = lane & 15;   // phase 1 mapping
    const int ogi   = lane & 31, csi   = lane >> 5;   // phase 2 mapping
    const int ib    = ogi * 9;

    float r9[9];
    #pragma unroll
    for (int j = 0; j < 9; ++j) r9[j] = 0.f;

    #pragma unroll 1
    for (int r = 0; r < 4; ++r) {
        // ---- phase 1: x update, channels 16w+4r+{0..3} ----
        {
            const int c = wv * 16 + r * 4 + cb2;
            float* xrow = xs + (wv * 4 + cb2) * XS_C;
            const size_t xg = ((size_t)(b * CCH + c)) * MM;
            const float* hr = Hs + c * HS_P;
            #pragma unroll
            for (int p = 0; p < 2; ++p) {
                const int lb = p * 128 + lanem * 8;
                const int mb = m0 + lb;
                const size_t g = xg + mb;
                const bool fast = (mb + 7 < MM);
                float av[8], bv[8];
                if (fast) {   // longest-latency loads first
                    #pragma unroll
                    for (int j = 0; j < 8; j += 2) {
                        float2 t2 = *(const float2*)(xA + g + j);
                        av[j] = t2.x; av[j + 1] = t2.y;
                    }
                    #pragma unroll
                    for (int j = 0; j < 8; j += 2) {
                        float2 t2 = *(const float2*)(xW + g + j);
                        bv[j] = t2.x; bv[j + 1] = t2.y;
                    }
                }
                // ring preload: 16 values = 4x b128
                float w[16];
                #pragma unroll
                for (int q = 0; q < 4; ++q) {
                    float4 qv = *(const float4*)&resv[Fi(lb + 4 * q)];
                    w[4 * q] = qv.x; w[4 * q + 1] = qv.y;
                    w[4 * q + 2] = qv.z; w[4 * q + 3] = qv.w;
                }
                float h4[4];
                #pragma unroll
                for (int i2 = 0; i2 < 4; ++i2) h4[i2] = hr[i2];
                float acc[8];
                #pragma unroll
                for (int j = 0; j < 8; ++j) acc[j] = 0.f;
                // 8 blocks of 4 taps (taps 31..: h=0 pad)
                #pragma unroll
                for (int kb = 0; kb < 32; kb += 4) {
                    float hn[4];
                    if (kb < 28) {
                        #pragma unroll
                        for (int i2 = 0; i2 < 4; ++i2) hn[i2] = hr[kb + 4 + i2];
                    }
                    float4 rq;
                    if (kb < 24) rq = *(const float4*)&resv[Fi(lb + kb + 16)];
                    #pragma unroll
                    for (int kk = 0; kk < 4; ++kk) {
                        const int k = kb + kk;
                        const float h = h4[kk];
                        #pragma unroll
                        for (int j = 0; j < 8; ++j)
                            acc[j] = fmaf(w[(k + j) & 15], h, acc[j]);
                    }
                    if (kb < 24) {
                        w[(kb + 0) & 15] = rq.x; w[(kb + 1) & 15] = rq.y;
                        w[(kb + 2) & 15] = rq.z; w[(kb + 3) & 15] = rq.w;
                    }
                    if (kb < 28) {
                        #pragma unroll
                        for (int i2 = 0; i2 < 4; ++i2) h4[i2] = hn[i2];
                    }
                }
                if (fast) {
                    float xn[8], x1[8];
                    #pragma unroll
                    for (int j = 0; j < 8; ++j) {
                        float xt = fmaf(c0, av[j] - bv[j], av[j]);      // x_tmp_t
                        xn[j] = fmaxf(fmaf(acc[j], 0.2f, xt) - 0.02f, 0.f);
                        x1[j] = fmaf(c1, xn[j] - av[j], xn[j]);         // x_tmp_{t+1}
                    }
                    *(float4*)&xrow[Fi(32 + lb)] =
                        make_float4(x1[0], x1[1], x1[2], x1[3]);
                    *(float4*)&xrow[Fi(32 + lb + 4)] =
                        make_float4(x1[4], x1[5], x1[6], x1[7]);
                    #pragma unroll
                    for (int j = 0; j < 8; j += 2)
                        *(float2*)(xW + g + j) = make_float2(xn[j], xn[j + 1]);
                } else {
                    #pragma unroll
                    for (int j = 0; j < 8; ++j) {
                        float x1 = 0.f;
                        if (mb + j < MM) {
                            float a = xA[g + j], b2 = xW[g + j];
                            float xt = fmaf(c0, a - b2, a);
                            float v  = fmaxf(fmaf(acc[j], 0.2f, xt) - 0.02f, 0.f);
                            xW[g + j] = v;
                            x1 = fmaf(c1, v - a, v);
                        }
                        xrow[Fi(32 + lb + j)] = x1;
                    }
                }
            }
        }

        // ---- phase 2: Hop gather of same 4 channels (intra-wave dep) ----
        #pragma unroll
        for (int cc = 0; cc < 2; ++cc) {
            const int cl = 2 * csi + cc;
            const float* xr = xs + (wv * 4 + cl) * XS_C;
            const float* hc = Hs + (wv * 16 + r * 4 + cl) * HS_P;
            // ring holds x[ib-7 .. ib+8]; slot(m) = (m+7)&15
            float w[16];
            #pragma unroll
            for (int s = 0; s < 16; ++s) w[s] = xr[Fi(32 + ib - 7 + s)];
            float h4[4];
            #pragma unroll
            for (int i2 = 0; i2 < 4; ++i2) h4[i2] = hc[i2];
            #pragma unroll
            for (int kb = 0; kb < 32; kb += 4) {
                float hn[4];
                if (kb < 28) {
                    #pragma unroll
                    for (int i2 = 0; i2 < 4; ++i2) hn[i2] = hc[kb + 4 + i2];
                }
                float rv[4];
                if (kb < 24) {   // load x[ib-8-k], used at tap k+8
                    #pragma unroll
                    for (int i2 = 0; i2 < 4; ++i2)
                        rv[i2] = xr[Fi(32 + ib - 8 - (kb + i2))];
                }
                #pragma unroll
                for (int kk = 0; kk < 4; ++kk) {
                    const int k = kb + kk;
                    const float h = h4[kk];
                    #pragma unroll
                    for (int j = 0; j < 9; ++j)
                        r9[j] = fmaf(w[(j - k + 7) & 15], h, r9[j]);
                }
                if (kb < 24) {
                    #pragma unroll
                    for (int i2 = 0; i2 < 4; ++i2)
                        w[(15 - (kb + i2)) & 15] = rv[i2];
                }
                if (kb < 28) {
                    #pragma unroll
                    for (int i2 = 0; i2 < 4; ++i2) h4[i2] = hn[i2];
                }
            }
        }
    }

    // ---- flush: combine csi pair, per-wave LDS row, then global atomics ----
    #pragma unroll
    for (int j = 0; j < 9; ++j) r9[j] += __shfl_xor(r9[j], 32);
    if (lane < 32) {
        #pragma unroll
        for (int j = 0; j < 9; ++j) racc[wv * RACC_P + ib + j] = r9[j];
    }
    __syncthreads();
    for (int i = tid; i < 286; i += 256) {
        int n = m0 + i;
        if (n < NN) {
            float s4 = racc[i] + racc[RACC_P + i] +
                       racc[2 * RACC_P + i] + racc[3 * RACC_P + i];
            atomicAdd(&rnext[yb + n], s4);
        }
    }
}

extern "C" void kernel_launch(void* const* d_in, const int* in_sizes, int n_in,
                              void* d_out, int out_size, void* d_ws, size_t ws_size,
                              hipStream_t stream) {
    const float* y  = (const float*)d_in[0];
    const float* Hg = (const float*)d_in[1];

    float* out  = (float*)d_out;
    float* yhat = out;               // B*N
    float* xout = out + BN;          // B*C*M : ping-pong X1 (odd t)
    float* x0w  = (float*)d_ws;      // B*C*M : ping-pong X0 (even t)
    float* r0   = x0w + BCM;         // 3 rotating Hop accumulators, B*N each
    float* r1   = r0 + BN;
    float* r2   = r1 + BN;
    float* rb[3] = {r0, r1, r2};

    hipMemsetAsync(x0w, 0, (BCM + 3 * BN) * sizeof(float), stream);
    hipMemsetAsync(out, 0, (BN + BCM) * sizeof(float), stream);

    dim3 grid(NT, BB);   // 1024 blocks
    float s = 1.f, beta_prev = 0.f;
    for (int t = 0; t < TT; ++t) {
        float snew = (1.f + sqrtf(1.f + 4.f * s * s)) * 0.5f;
        float beta = (s - 1.f) / snew;
        float c1v = (t == TT - 1) ? 0.f : beta;          // t=29: Hop(x_new)=y_hat
        float* xWt       = (t & 1) ? xout : x0w;
        const float* xAt = (t & 1) ? x0w  : xout;
        float* rnext = (t == TT - 1) ? yhat : rb[(t + 1) % 3];
        step_kernel<<<grid, 256, 0, stream>>>(y, Hg, xAt, xWt,
            rb[t % 3], rnext, rb[(t + 2) % 3], beta_prev, c1v);
        beta_prev = beta;
        s = snew;
    }
}

// Round 8
// 1915.952 us; speedup vs baseline: 4.2025x; 1.1728x over previous
//
#include <hip/hip_runtime.h>
#include <math.h>

// CRsAE1D: 30 FISTA iterations. y [32,1,8192] f32, H [64,1,31] f32.
// out = concat(y_hat [32,8192], x [32,64,8162]) f32.
//
// One fused kernel per iteration; block = (batch b, 384-wide m-tile);
// grid = 22x32 = 704 blocks -> fully co-resident at 3 blocks/CU (no
// serialized residency tail, round-6's ~33% loss). Wave w owns channels
// [16w,16w+16); per r it processes 4 channels (one per cb2 lane group):
//   phase1: x update (HT ring conv) -> xs rows, x_new -> global
//   phase2: Hop gather (descending ring) -> butterfly over cb2 -> racc
// H is re-laid out as interleaved quads [g=wv*4+r][quad][cb2][4] so each
// lane loads its channel's taps ONCE per r via 8 conflict-free b128 into
// 32 registers (shared by both phases). All ring reads are aligned b128
// with distance-2 prefetch. 2 barriers total.
//
// (Resubmission: round-7 bench died on GPU acquisition timeout before
// running; source unchanged.)

#define BB   32
#define CCH  64
#define KF   31
#define NN   8192
#define MM   8162
#define TT   30
#define TILE 384
#define NTI  22          // ceil(8192/384)
#define XS_C 500         // Fi(447)=499
#define RV_N 464         // Fi(415)=463
#define RP   464         // racc row pitch (Fi-indexed)

#define BCM ((size_t)BB * CCH * MM)
#define BN  ((size_t)BB * NN)

// LDS swizzle: +4 slots every 32 -> quad-aligned, breaks power-of-2 strides
__device__ __forceinline__ int Fi(int i) { return i + ((i >> 5) << 2); }

__global__ __launch_bounds__(256) void step_kernel(
    const float* __restrict__ y, const float* __restrict__ Hg,
    const float* __restrict__ xA,  // x_new_{t-1}
    float* __restrict__ xW,        // read: x_new_{t-2}; write: x_new_t
    const float* __restrict__ rcur, float* __restrict__ rnext,
    float* __restrict__ rzero, float c0, float c1)
{
    __shared__ __attribute__((aligned(16))) float Hs2[2048];      //  8192 B
    __shared__ __attribute__((aligned(16))) float resv[RV_N];     //  1856 B
    __shared__ __attribute__((aligned(16))) float xs[16 * XS_C];  // 32000 B
    __shared__ __attribute__((aligned(16))) float racc[4 * RP];   //  7424 B

    const int tid = threadIdx.x;
    const int m0  = blockIdx.x * TILE;
    const int b   = blockIdx.y;
    const size_t yb = (size_t)b * NN;

    // ---- staging ----
    // Hs2[g*128 + q*16 + cb*4 + e] = H[(g>>2)*16+(g&3)*4+cb][q*4+e] (pad 0)
    for (int s = tid; s < 2048; s += 256) {
        int g = s >> 7, rem = s & 127;
        int q = rem >> 4, sl = rem & 15;
        int cb = sl >> 2, e = sl & 3;
        int c = (g >> 2) * 16 + (g & 3) * 4 + cb;
        int tap = q * 4 + e;
        Hs2[s] = (tap < KF) ? Hg[c * KF + tap] : 0.f;
    }
    for (int i = tid; i < 416; i += 256) {
        int n = m0 + i; float v = 0.f;
        if (i < 414 && n < NN) v = y[yb + n] - rcur[yb + n];
        resv[Fi(i)] = v;
    }
    for (int s = tid; s < 16 * 64; s += 256) {   // xs halos: raw [0,32)+[416,448)
        int row = s >> 6, q = s & 63;
        int raw = (q < 32) ? q : (q + 384);
        xs[row * XS_C + Fi(raw)] = 0.f;
    }
    for (int s = tid; s < 4 * RP; s += 256) racc[s] = 0.f;
    for (int i = tid; i < TILE; i += 256) {      // pre-zero t+2 accumulator
        int n = m0 + i;
        if (n < NN) rzero[yb + n] = 0.f;
    }
    __syncthreads();

    const int wv    = tid >> 6, lane = tid & 63;
    const int cb2   = lane >> 4, lanem = lane & 15;

    #pragma unroll 1
    for (int r = 0; r < 4; ++r) {
        const int c = wv * 16 + r * 4 + cb2;
        float* xrow = xs + (wv * 4 + cb2) * XS_C;
        const size_t xg = ((size_t)(b * CCH + c)) * MM;

        // h taps for this lane's channel: 8 conflict-free b128 -> 32 regs
        float hv[32];
        {
            const int hb = (wv * 4 + r) * 128 + cb2 * 4;
            #pragma unroll
            for (int q = 0; q < 8; ++q) {
                float4 t = *(const float4*)&Hs2[hb + q * 16];
                hv[q*4] = t.x; hv[q*4+1] = t.y; hv[q*4+2] = t.z; hv[q*4+3] = t.w;
            }
        }

        // ---- phase 1: x update (ascending ring, distance-2 prefetch) ----
        #pragma unroll 1
        for (int p = 0; p < 3; ++p) {
            const int lb = p * 128 + lanem * 8;
            const int mb = m0 + lb;
            const size_t g = xg + mb;
            const bool fast = (mb + 7 < MM);
            float av[8], bv[8];
            if (fast) {
                #pragma unroll
                for (int j = 0; j < 8; j += 2) {
                    float2 t2 = *(const float2*)(xA + g + j);
                    av[j] = t2.x; av[j + 1] = t2.y;
                }
                #pragma unroll
                for (int j = 0; j < 8; j += 2) {
                    float2 t2 = *(const float2*)(xW + g + j);
                    bv[j] = t2.x; bv[j + 1] = t2.y;
                }
            }
            float w[16];
            #pragma unroll
            for (int q = 0; q < 4; ++q) {
                float4 v = *(const float4*)&resv[Fi(lb + 4 * q)];
                w[4*q] = v.x; w[4*q+1] = v.y; w[4*q+2] = v.z; w[4*q+3] = v.w;
            }
            float acc[8];
            #pragma unroll
            for (int j = 0; j < 8; ++j) acc[j] = 0.f;
            #pragma unroll
            for (int kb = 0; kb < 32; kb += 4) {
                float4 rq;
                if (kb <= 20) rq = *(const float4*)&resv[Fi(lb + 16 + kb)];
                #pragma unroll
                for (int kk = 0; kk < 4; ++kk) {
                    const float h = hv[kb + kk];
                    #pragma unroll
                    for (int j = 0; j < 8; ++j)
                        acc[j] = fmaf(w[(kb + kk + j) & 15], h, acc[j]);
                }
                if (kb <= 20) {
                    w[kb & 15] = rq.x; w[(kb+1) & 15] = rq.y;
                    w[(kb+2) & 15] = rq.z; w[(kb+3) & 15] = rq.w;
                }
            }
            if (fast) {
                float xn[8], x1[8];
                #pragma unroll
                for (int j = 0; j < 8; ++j) {
                    float xt = fmaf(c0, av[j] - bv[j], av[j]);      // x_tmp_t
                    xn[j] = fmaxf(fmaf(acc[j], 0.2f, xt) - 0.02f, 0.f);
                    x1[j] = fmaf(c1, xn[j] - av[j], xn[j]);         // x_tmp_{t+1}
                }
                *(float4*)&xrow[Fi(32 + lb)] =
                    make_float4(x1[0], x1[1], x1[2], x1[3]);
                *(float4*)&xrow[Fi(36 + lb)] =
                    make_float4(x1[4], x1[5], x1[6], x1[7]);
                #pragma unroll
                for (int j = 0; j < 8; j += 2)
                    *(float2*)(xW + g + j) = make_float2(xn[j], xn[j + 1]);
            } else {
                #pragma unroll
                for (int j = 0; j < 8; ++j) {
                    float x1 = 0.f;
                    if (mb + j < MM) {
                        float a = xA[g + j], b2 = xW[g + j];
                        float xt = fmaf(c0, a - b2, a);
                        float v  = fmaxf(fmaf(acc[j], 0.2f, xt) - 0.02f, 0.f);
                        xW[g + j] = v;
                        x1 = fmaf(c1, v - a, v);
                    }
                    xrow[Fi(32 + lb + j)] = x1;
                }
            }
        }

        // ---- phase 2: Hop gather (descending ring, distance-2 prefetch) ----
        // slot(m) = (m - (lb-8)) & 15
        #pragma unroll 1
        for (int p2 = 0; p2 < 3; ++p2) {
            const int lb = p2 * 128 + lanem * 8;
            float w[16];
            #pragma unroll
            for (int q = 0; q < 4; ++q) {
                float4 v = *(const float4*)&xrow[Fi(24 + lb + 4 * q)];
                w[4*q] = v.x; w[4*q+1] = v.y; w[4*q+2] = v.z; w[4*q+3] = v.w;
            }
            float a8[8];
            #pragma unroll
            for (int j = 0; j < 8; ++j) a8[j] = 0.f;
            #pragma unroll
            for (int kb = 0; kb < 32; kb += 4) {
                float4 rq;
                if (kb <= 20) rq = *(const float4*)&xrow[Fi(20 + lb - kb)];
                #pragma unroll
                for (int kk = 0; kk < 4; ++kk) {
                    const float h = hv[kb + kk];
                    #pragma unroll
                    for (int j = 0; j < 8; ++j)
                        a8[j] = fmaf(w[(j - kb - kk + 8) & 15], h, a8[j]);
                }
                if (kb <= 20) {
                    w[(12 - kb) & 15] = rq.x; w[(13 - kb) & 15] = rq.y;
                    w[(14 - kb) & 15] = rq.z; w[(15 - kb) & 15] = rq.w;
                }
            }
            #pragma unroll
            for (int j = 0; j < 8; ++j) {
                a8[j] += __shfl_xor(a8[j], 16);
                a8[j] += __shfl_xor(a8[j], 32);
            }
            if (cb2 == 0) {
                #pragma unroll
                for (int j = 0; j < 8; ++j)
                    racc[wv * RP + Fi(lb + j)] += a8[j];
            }
        }

        // ---- phase 2 tail: outputs 384..413 (2 per lanem) ----
        {
            const int lbt = 384 + lanem * 2;
            float w[33];                       // x[lbt-31 .. lbt+1]
            #pragma unroll
            for (int s = 0; s < 33; ++s) w[s] = xrow[Fi(1 + lbt + s)];
            float t0 = 0.f, t1 = 0.f;
            #pragma unroll
            for (int k = 0; k < KF; ++k) {
                t0 = fmaf(w[31 - k], hv[k], t0);
                t1 = fmaf(w[32 - k], hv[k], t1);
            }
            t0 += __shfl_xor(t0, 16); t0 += __shfl_xor(t0, 32);
            t1 += __shfl_xor(t1, 16); t1 += __shfl_xor(t1, 32);
            if (cb2 == 0) {
                if (lbt < 414)     racc[wv * RP + Fi(lbt)]     += t0;
                if (lbt + 1 < 414) racc[wv * RP + Fi(lbt + 1)] += t1;
            }
        }
    }

    // ---- flush: sum 4 wave rows, one global atomic per output ----
    __syncthreads();
    for (int i = tid; i < 414; i += 256) {
        int n = m0 + i;
        if (n < NN) {
            int f = Fi(i);
            float s4 = racc[f] + racc[RP + f] + racc[2 * RP + f] + racc[3 * RP + f];
            atomicAdd(&rnext[yb + n], s4);
        }
    }
}

extern "C" void kernel_launch(void* const* d_in, const int* in_sizes, int n_in,
                              void* d_out, int out_size, void* d_ws, size_t ws_size,
                              hipStream_t stream) {
    const float* y  = (const float*)d_in[0];
    const float* Hg = (const float*)d_in[1];

    float* out  = (float*)d_out;
    float* yhat = out;               // B*N
    float* xout = out + BN;          // B*C*M : ping-pong X1 (odd t)
    float* x0w  = (float*)d_ws;      // B*C*M : ping-pong X0 (even t)
    float* r0   = x0w + BCM;         // 3 rotating Hop accumulators, B*N each
    float* r1   = r0 + BN;
    float* r2   = r1 + BN;
    float* rb[3] = {r0, r1, r2};

    hipMemsetAsync(x0w, 0, (BCM + 3 * BN) * sizeof(float), stream);
    hipMemsetAsync(out, 0, (BN + BCM) * sizeof(float), stream);

    dim3 grid(NTI, BB);   // 22 x 32 = 704 blocks: fully co-resident at 3/CU
    float s = 1.f, beta_prev = 0.f;
    for (int t = 0; t < TT; ++t) {
        float snew = (1.f + sqrtf(1.f + 4.f * s * s)) * 0.5f;
        float beta = (s - 1.f) / snew;
        float c1v = (t == TT - 1) ? 0.f : beta;          // t=29: Hop(x_new)=y_hat
        float* xWt       = (t & 1) ? xout : x0w;
        const float* xAt = (t & 1) ? x0w  : xout;
        float* rnext = (t == TT - 1) ? yhat : rb[(t + 1) % 3];
        step_kernel<<<grid, 256, 0, stream>>>(y, Hg, xAt, xWt,
            rb[t % 3], rnext, rb[(t + 2) % 3], beta_prev, c1v);
        beta_prev = beta;
        s = snew;
    }
}